// Round 4
// baseline (395.573 us; speedup 1.0000x reference)
//
#include <hip/hip_runtime.h>

// ---------- types ----------
typedef __bf16 bf16x8 __attribute__((ext_vector_type(8)));
typedef __bf16 bf16x4 __attribute__((ext_vector_type(4)));
typedef float  f32x4  __attribute__((ext_vector_type(4)));

// async global->LDS, 16B per lane; LDS dest = wave-uniform base + lane*16
__device__ __forceinline__ void cp16(void* lds, const void* g) {
  __builtin_amdgcn_global_load_lds(
      (const __attribute__((address_space(1))) unsigned int*)g,
      (__attribute__((address_space(3))) unsigned int*)lds, 16, 0, 0);
}

// =====================================================================
// Fused small conversions: Wq->Wqb, Wk->Wkvb[0:], Wv->Wkvb[131072:], T->Tbf
// 655360 elems total, 4/thread, 640 blocks.
// =====================================================================
__global__ __launch_bounds__(256) void cvt_small(const float* __restrict__ Wq,
                                                 const float* __restrict__ Wk,
                                                 const float* __restrict__ Wv,
                                                 const float* __restrict__ T,
                                                 __bf16* __restrict__ Wqb,
                                                 __bf16* __restrict__ Wkvb,
                                                 __bf16* __restrict__ Tbf) {
  const int idx = (blockIdx.x * 256 + threadIdx.x) * 4;
  const float* src;
  __bf16* dst;
  int o;
  if (idx < 131072)      { o = idx;          src = Wq; dst = Wqb; }
  else if (idx < 262144) { o = idx - 131072; src = Wk; dst = Wkvb; }
  else if (idx < 393216) { o = idx - 262144; src = Wv; dst = Wkvb + 131072; }
  else                   { o = idx - 393216; src = T;  dst = Tbf; }
  f32x4 v = *(const f32x4*)(src + o);
  bf16x4 b;
  b[0] = (__bf16)v[0]; b[1] = (__bf16)v[1];
  b[2] = (__bf16)v[2]; b[3] = (__bf16)v[3];
  *(bf16x4*)(dst + o) = b;
}

// =====================================================================
// gemm_kv: per block, 128 E-rows x 256 W-rows, K=512, BK=32.
// y=0: W=Wk  -> Kp[n][d]   (row-major, stride 256, bf16x4 stores)
// y=1: W=Wv  -> Vt[d][n]   (transposed, stride 65536, scalar bf16 stores)
// E read directly as f32, converted to bf16 at fragment build.
// 4 waves: wm=w>>1 (m half of 128), wn=w&1 (n half of 64). acc[8][4].
// =====================================================================
__global__ __launch_bounds__(256) void gemm_kv(const float* __restrict__ E,
                                               const __bf16* __restrict__ Wkv,
                                               __bf16* __restrict__ Kp,
                                               __bf16* __restrict__ Vt) {
  __shared__ __align__(16) float  Et[128 * 32];   // 16 KB
  __shared__ __align__(16) __bf16 Wt[256 * 32];   // 16 KB
  const int tid = threadIdx.x;
  const int lane = tid & 63;
  const int q = lane >> 4, ln = lane & 15;
  const int w = tid >> 6;
  const int wm = w >> 1, wn = w & 1;
  const int nbase = blockIdx.x * 128;
  const int yy = blockIdx.y;
  const __bf16* Wb = Wkv + yy * 131072;   // 256 rows x 512

  f32x4 acc[8][4] = {};

  for (int kt = 0; kt < 16; ++kt) {
    const int k0 = kt * 32;
    __syncthreads();
#pragma unroll
    for (int s = 0; s < 4; ++s) {
      const int cbase = (tid & 192) + s * 256;  // wave-uniform, 1024 chunks
      const int c = cbase + lane;
      // Wt: 4 chunks/row (32 bf16), Et: 8 chunks/row (32 f32)
      const int wrow = c >> 2, wkc = (c & 3) * 8;
      const int erow = c >> 3, ekc = (c & 7) * 4;
      cp16(&Wt[cbase * 8], Wb + (size_t)wrow * 512 + k0 + wkc);
      cp16(&Et[cbase * 4], E + (size_t)(nbase + erow) * 512 + k0 + ekc);
    }
    __syncthreads();

    bf16x8 af[8];
#pragma unroll
    for (int fm = 0; fm < 8; ++fm)
      af[fm] = *(const bf16x8*)&Wt[(wm * 128 + fm * 16 + ln) * 32 + q * 8];
    bf16x8 bfr[4];
#pragma unroll
    for (int fn = 0; fn < 4; ++fn) {
      const float* p = &Et[(wn * 64 + fn * 16 + ln) * 32 + q * 8];
      f32x4 v0 = *(const f32x4*)p;
      f32x4 v1 = *(const f32x4*)(p + 4);
      bf16x8 bb;
      bb[0] = (__bf16)v0[0]; bb[1] = (__bf16)v0[1];
      bb[2] = (__bf16)v0[2]; bb[3] = (__bf16)v0[3];
      bb[4] = (__bf16)v1[0]; bb[5] = (__bf16)v1[1];
      bb[6] = (__bf16)v1[2]; bb[7] = (__bf16)v1[3];
      bfr[fn] = bb;
    }
#pragma unroll
    for (int fm = 0; fm < 8; ++fm)
#pragma unroll
      for (int fn = 0; fn < 4; ++fn)
        acc[fm][fn] = __builtin_amdgcn_mfma_f32_16x16x32_bf16(
            af[fm], bfr[fn], acc[fm][fn], 0, 0, 0);
  }

  if (yy == 0) {
    // Kp[n*256 + m], lane holds m = base + q*4 + r (consecutive) -> 8B stores
#pragma unroll
    for (int fm = 0; fm < 8; ++fm)
#pragma unroll
      for (int fn = 0; fn < 4; ++fn) {
        const int m = wm * 128 + fm * 16 + q * 4;
        const int n = nbase + wn * 64 + fn * 16 + ln;
        f32x4 v = acc[fm][fn];
        bf16x4 o;
        o[0] = (__bf16)v[0]; o[1] = (__bf16)v[1];
        o[2] = (__bf16)v[2]; o[3] = (__bf16)v[3];
        *(bf16x4*)&Kp[(size_t)n * 256 + m] = o;
      }
  } else {
    // Vt[d*65536 + n], d = m index: scalar bf16 stores (coalesced in n per ln)
#pragma unroll
    for (int fm = 0; fm < 8; ++fm)
#pragma unroll
      for (int fn = 0; fn < 4; ++fn) {
        const int n = nbase + wn * 64 + fn * 16 + ln;
        f32x4 v = acc[fm][fn];
#pragma unroll
        for (int r = 0; r < 4; ++r) {
          const int d = wm * 128 + fm * 16 + q * 4 + r;
          Vt[(size_t)d * 65536 + n] = (__bf16)v[r];
        }
      }
  }
}

// =====================================================================
// GEMM (Q only): out[n*256 + m] = sum_k A[m][k]*B[n][k], k=512, bf16 in.
// m97 structure: 128x128 tile, BK=32, 4 waves 2x2, 4x4 frags.
// =====================================================================
__global__ __launch_bounds__(256) void gemm_nt(const __bf16* __restrict__ Aop,
                                               const __bf16* __restrict__ Bop,
                                               __bf16* __restrict__ out) {
  __shared__ __align__(16) __bf16 At[128 * 32];
  __shared__ __align__(16) __bf16 Bt[128 * 32];
  const int tid = threadIdx.x;
  const int lane = tid & 63;
  const int w = tid >> 6;
  const int q = lane >> 4, ln = lane & 15;
  const int wm = w >> 1, wn = w & 1;
  const int nbase = blockIdx.x * 128, mbase = blockIdx.y * 128;

  f32x4 acc[4][4] = {};

  for (int kt = 0; kt < 16; ++kt) {
    const int k0 = kt * 32;
    __syncthreads();
#pragma unroll
    for (int s = 0; s < 2; ++s) {
      const int cbase = (tid & 192) + s * 256;
      const int c = cbase + lane;
      const int row = c >> 2;
      const int kc = (c & 3) * 8;
      cp16(&At[cbase * 8], Aop + (size_t)(mbase + row) * 512 + k0 + kc);
      cp16(&Bt[cbase * 8], Bop + (size_t)(nbase + row) * 512 + k0 + kc);
    }
    __syncthreads();

    bf16x8 af[4], bfr[4];
#pragma unroll
    for (int f = 0; f < 4; ++f) {
      af[f]  = *(const bf16x8*)&At[(wm * 64 + f * 16 + ln) * 32 + q * 8];
      bfr[f] = *(const bf16x8*)&Bt[(wn * 64 + f * 16 + ln) * 32 + q * 8];
    }
#pragma unroll
    for (int fm = 0; fm < 4; ++fm)
#pragma unroll
      for (int fn = 0; fn < 4; ++fn)
        acc[fm][fn] = __builtin_amdgcn_mfma_f32_16x16x32_bf16(
            af[fm], bfr[fn], acc[fm][fn], 0, 0, 0);
  }

#pragma unroll
  for (int fm = 0; fm < 4; ++fm)
#pragma unroll
    for (int fn = 0; fn < 4; ++fn) {
      const int m = mbase + wm * 64 + fm * 16 + q * 4;
      const int n = nbase + wn * 64 + fn * 16 + ln;
      f32x4 v = acc[fm][fn];
      bf16x4 o;
      o[0] = (__bf16)v[0]; o[1] = (__bf16)v[1];
      o[2] = (__bf16)v[2]; o[3] = (__bf16)v[3];
      *(bf16x4*)&out[(size_t)n * 256 + m] = o;
    }
}

// =====================================================================
// Attention: per (n-chunk cx, batch b): S = Q Kp^T/16 + logP, P=exp(S)
// (scores tiny + logP in [-2.3,-0.105] -> no max pass). Writes:
//   Pws (bf16, unnormalized), rowsum (atomic, small), Opart plane cx (f32).
// =====================================================================
#define QLDS_STRIDE 264
#define PLDS_STRIDE 136
__global__ __launch_bounds__(256) void attn_kernel(
    const __bf16* __restrict__ Qw, const __bf16* __restrict__ Kp,
    const __bf16* __restrict__ Vt, const float* __restrict__ Pb,
    __bf16* __restrict__ Pws, float* __restrict__ Opart,
    float* __restrict__ rowsum) {
  __shared__ __align__(16) __bf16 Qlds[32 * QLDS_STRIDE];
  __shared__ __align__(16) __bf16 Ktile[128 * 32];
  __shared__ __align__(16) __bf16 Plds[32 * PLDS_STRIDE];

  const int tid = threadIdx.x;
  const int lane = tid & 63;
  const int w = tid >> 6;
  const int q = lane >> 4, ln = lane & 15;
  const int b = blockIdx.y;
  const int cx = blockIdx.x;
  const int n0 = cx * 128;

  // stage Q_b [32 x 256] into padded LDS
  const __bf16* Qb = Qw + (size_t)b * 32 * 256;
#pragma unroll
  for (int s = 0; s < 4; ++s) {
    const int c = tid + s * 256;
    const int row = c >> 5, col = (c & 31) * 8;
    bf16x8 v = *(const bf16x8*)(Qb + (size_t)c * 8);
    *(bf16x8*)&Qlds[row * QLDS_STRIDE + col] = v;
  }

  // ---- QK^T ----
  f32x4 acc[2][2] = {};
  const __bf16* Kpb = Kp + (size_t)(b * 4096 + n0) * 256;
  for (int kk = 0; kk < 8; ++kk) {
    __syncthreads();
#pragma unroll
    for (int s = 0; s < 2; ++s) {
      const int cbase = (tid & 192) + s * 256;
      const int c = cbase + lane;
      const int row = c >> 2;
      const int kc = (c & 3) * 8;
      cp16(&Ktile[cbase * 8], Kpb + (size_t)row * 256 + kk * 32 + kc);
    }
    __syncthreads();
    bf16x8 a0 = *(const bf16x8*)&Qlds[(ln) * QLDS_STRIDE + kk * 32 + q * 8];
    bf16x8 a1 = *(const bf16x8*)&Qlds[(16 + ln) * QLDS_STRIDE + kk * 32 + q * 8];
    bf16x8 b0 = *(const bf16x8*)&Ktile[(w * 32 + ln) * 32 + q * 8];
    bf16x8 b1 = *(const bf16x8*)&Ktile[(w * 32 + 16 + ln) * 32 + q * 8];
    acc[0][0] = __builtin_amdgcn_mfma_f32_16x16x32_bf16(a0, b0, acc[0][0], 0, 0, 0);
    acc[0][1] = __builtin_amdgcn_mfma_f32_16x16x32_bf16(a0, b1, acc[0][1], 0, 0, 0);
    acc[1][0] = __builtin_amdgcn_mfma_f32_16x16x32_bf16(a1, b0, acc[1][0], 0, 0, 0);
    acc[1][1] = __builtin_amdgcn_mfma_f32_16x16x32_bf16(a1, b1, acc[1][1], 0, 0, 0);
  }

  // ---- P = exp(S/16 + logP) ----
  float lp[2];
#pragma unroll
  for (int fn = 0; fn < 2; ++fn) {
    const int n = n0 + w * 32 + fn * 16 + ln;
    float p = Pb[b * 4096 + n];
    p = fminf(fmaxf(p, 0.1f), 0.9f);
    lp[fn] = __logf(p);
  }
  float rs[2][4] = {};
#pragma unroll
  for (int fm = 0; fm < 2; ++fm) {
#pragma unroll
    for (int fn = 0; fn < 2; ++fn) {
      f32x4 s = acc[fm][fn];
#pragma unroll
      for (int r = 0; r < 4; ++r) {
        const float pv = __expf(s[r] * 0.0625f + lp[fn]);
        const int i = fm * 16 + q * 4 + r;
        const int nn = w * 32 + fn * 16 + ln;
        const __bf16 pbv = (__bf16)pv;
        Pws[(size_t)(b * 32 + i) * 4096 + n0 + nn] = pbv;
        Plds[i * PLDS_STRIDE + nn] = pbv;
        rs[fm][r] += pv;
      }
    }
  }
#pragma unroll
  for (int m = 1; m < 16; m <<= 1)
#pragma unroll
    for (int fm = 0; fm < 2; ++fm)
#pragma unroll
      for (int r = 0; r < 4; ++r)
        rs[fm][r] += __shfl_xor(rs[fm][r], m, 64);
  if (ln == 0) {
#pragma unroll
    for (int fm = 0; fm < 2; ++fm)
#pragma unroll
      for (int r = 0; r < 4; ++r)
        atomicAdd(&rowsum[b * 32 + fm * 16 + q * 4 + r], rs[fm][r]);
  }
  __syncthreads();

  // ---- PV partial -> Opart plane cx (plain stores, no atomics) ----
  f32x4 acc2[2][4] = {};
  const __bf16* Vtb = Vt + (size_t)b * 4096 + n0;
  for (int kk = 0; kk < 4; ++kk) {
    bf16x8 pa0 = *(const bf16x8*)&Plds[(ln) * PLDS_STRIDE + kk * 32 + q * 8];
    bf16x8 pa1 = *(const bf16x8*)&Plds[(16 + ln) * PLDS_STRIDE + kk * 32 + q * 8];
    bf16x8 vb[4];
#pragma unroll
    for (int fd = 0; fd < 4; ++fd) {
      const int d = w * 64 + fd * 16 + ln;
      vb[fd] = *(const bf16x8*)(Vtb + (size_t)d * 65536 + kk * 32 + q * 8);
    }
#pragma unroll
    for (int fd = 0; fd < 4; ++fd) {
      acc2[0][fd] = __builtin_amdgcn_mfma_f32_16x16x32_bf16(pa0, vb[fd], acc2[0][fd], 0, 0, 0);
      acc2[1][fd] = __builtin_amdgcn_mfma_f32_16x16x32_bf16(pa1, vb[fd], acc2[1][fd], 0, 0, 0);
    }
  }
  float* Op = Opart + (size_t)cx * 131072;
#pragma unroll
  for (int fm = 0; fm < 2; ++fm)
#pragma unroll
    for (int fd = 0; fd < 4; ++fd)
#pragma unroll
      for (int r = 0; r < 4; ++r) {
        const int i = fm * 16 + q * 4 + r;
        const int d = w * 64 + fd * 16 + ln;
        Op[(size_t)(b * 32 + i) * 256 + d] = acc2[fm][fd][r];
      }
}

// =====================================================================
// norm_p: A(f32) = Pws(bf16) / rowsum[row]. 4 elems/thread, 2048 blocks.
// =====================================================================
__global__ __launch_bounds__(256) void norm_p(const __bf16* __restrict__ Pws,
                                              const float* __restrict__ rowsum,
                                              float* __restrict__ Aout) {
  const size_t idx = ((size_t)blockIdx.x * 256 + threadIdx.x) * 4;
  const int row = (int)(idx >> 12);
  const float invs = 1.0f / rowsum[row];
  bf16x4 p = *(const bf16x4*)(Pws + idx);
  f32x4 o;
  o[0] = (float)p[0] * invs; o[1] = (float)p[1] * invs;
  o[2] = (float)p[2] * invs; o[3] = (float)p[3] * invs;
  *(f32x4*)(Aout + idx) = o;
}

// =====================================================================
// final: reduce 32 Opart planes -> F1 row; F2 = (F1/rowsum)@Wo^T; L2 norm.
// one block per output row (b*32+i), 256 threads, 2 m's each. Wo f32.
// =====================================================================
__global__ __launch_bounds__(256) void final_kernel(const float* __restrict__ Opart,
                                                    const float* __restrict__ rowsum,
                                                    const float* __restrict__ Wo,
                                                    float* __restrict__ Fout) {
  __shared__ float fl[256];
  __shared__ float redbuf[4];
  const int row = blockIdx.x;
  const int t = threadIdx.x;
  float s = 0.f;
#pragma unroll
  for (int c = 0; c < 32; ++c)
    s += Opart[(size_t)c * 131072 + (size_t)row * 256 + t];
  fl[t] = s;
  __syncthreads();
  const float invs = 1.0f / rowsum[row];
  float f2[2];
#pragma unroll
  for (int h = 0; h < 2; ++h) {
    const int m = t + h * 256;
    const float* wr = Wo + (size_t)m * 256;
    float dot = 0.f;
    for (int d = 0; d < 256; d += 4) {
      f32x4 wv = *(const f32x4*)(wr + d);
      dot += wv[0] * fl[d] + wv[1] * fl[d + 1] + wv[2] * fl[d + 2] + wv[3] * fl[d + 3];
    }
    f2[h] = dot * invs;
  }
  float ps = f2[0] * f2[0] + f2[1] * f2[1];
#pragma unroll
  for (int m = 1; m < 64; m <<= 1) ps += __shfl_xor(ps, m, 64);
  if ((t & 63) == 0) redbuf[t >> 6] = ps;
  __syncthreads();
  const float tot = redbuf[0] + redbuf[1] + redbuf[2] + redbuf[3];
  const float sc = 1.0f / (sqrtf(tot) + 1e-8f);
  Fout[(size_t)row * 512 + t] = f2[0] * sc;
  Fout[(size_t)row * 512 + t + 256] = f2[1] * sc;
}

// =====================================================================
extern "C" void kernel_launch(void* const* d_in, const int* in_sizes, int n_in,
                              void* d_out, int out_size, void* d_ws, size_t ws_size,
                              hipStream_t stream) {
  const float* E  = (const float*)d_in[0];  // [16,4096,512]
  const float* T  = (const float*)d_in[1];  // [16,32,512]
  const float* Pb = (const float*)d_in[2];  // [16,4096]
  const float* Wq = (const float*)d_in[3];  // [256,512]
  const float* Wk = (const float*)d_in[4];
  const float* Wv = (const float*)d_in[5];
  const float* Wo = (const float*)d_in[6];  // [512,256]

  float* out  = (float*)d_out;
  float* Fout = out;             // [512][512] f32
  float* Aout = out + 262144;    // [512][4096] f32

  char* ws = (char*)d_ws;
  __bf16* Kp   = (__bf16*)ws;                   // [65536][256] bf16  33554432 B
  __bf16* Vt   = (__bf16*)(ws + 33554432);      // [256][65536] bf16  33554432 B
  __bf16* Pws  = (__bf16*)(ws + 67108864);      // [512][4096]  bf16   4194304 B
  float*  Opart= (float*)(ws + 71303168);       // [32][512][256] f32 16777216 B
  __bf16* Tbf  = (__bf16*)(ws + 88080384);      // 262144 elems         524288 B
  __bf16* Wqb  = (__bf16*)(ws + 88604672);      // 131072 elems         262144 B
  __bf16* Wkvb = (__bf16*)(ws + 88866816);      // 262144 elems         524288 B
  __bf16* Qw   = (__bf16*)(ws + 89391104);      // [512][256] bf16      262144 B
  float*  rowsum = (float*)(ws + 89653248);     // [512] f32 (2048 B)

  hipMemsetAsync(rowsum, 0, 2048, stream);

  cvt_small<<<640, 256, 0, stream>>>(Wq, Wk, Wv, T, Wqb, Wkvb, Tbf);

  // Q[row][d] = T @ Wq^T : A=Wqb (2 m-tiles), B=Tbf (4 n-tiles of 128 rows)
  gemm_nt<<<dim3(4, 2), 256, 0, stream>>>(Wqb, Tbf, Qw);

  // Kp + Vt in one launch, E read as f32 directly
  gemm_kv<<<dim3(512, 2), 256, 0, stream>>>(E, Wkvb, Kp, Vt);

  attn_kernel<<<dim3(32, 16), 256, 0, stream>>>(Qw, Kp, Vt, Pb, Pws, Opart, rowsum);
  norm_p<<<2048, 256, 0, stream>>>(Pws, rowsum, Aout);
  final_kernel<<<512, 256, 0, stream>>>(Opart, rowsum, Wo, Fout);
}

// Round 5
// 379.377 us; speedup vs baseline: 1.0427x; 1.0427x over previous
//
#include <hip/hip_runtime.h>

// ---------- types ----------
typedef __bf16 bf16x8 __attribute__((ext_vector_type(8)));
typedef __bf16 bf16x4 __attribute__((ext_vector_type(4)));
typedef float  f32x4  __attribute__((ext_vector_type(4)));

// async global->LDS, 16B per lane; LDS dest = wave-uniform base + lane*16
__device__ __forceinline__ void cp16(void* lds, const void* g) {
  __builtin_amdgcn_global_load_lds(
      (const __attribute__((address_space(1))) unsigned int*)g,
      (__attribute__((address_space(3))) unsigned int*)lds, 16, 0, 0);
}

// =====================================================================
// Fused small conversions: Wq->Wqb, Wk->Wkvb[0:], Wv->Wkvb[131072:], T->Tbf
// =====================================================================
__global__ __launch_bounds__(256) void cvt_small(const float* __restrict__ Wq,
                                                 const float* __restrict__ Wk,
                                                 const float* __restrict__ Wv,
                                                 const float* __restrict__ T,
                                                 __bf16* __restrict__ Wqb,
                                                 __bf16* __restrict__ Wkvb,
                                                 __bf16* __restrict__ Tbf) {
  const int idx = (blockIdx.x * 256 + threadIdx.x) * 4;
  const float* src;
  __bf16* dst;
  int o;
  if (idx < 131072)      { o = idx;          src = Wq; dst = Wqb; }
  else if (idx < 262144) { o = idx - 131072; src = Wk; dst = Wkvb; }
  else if (idx < 393216) { o = idx - 262144; src = Wv; dst = Wkvb + 131072; }
  else                   { o = idx - 393216; src = T;  dst = Tbf; }
  f32x4 v = *(const f32x4*)(src + o);
  bf16x4 b;
  b[0] = (__bf16)v[0]; b[1] = (__bf16)v[1];
  b[2] = (__bf16)v[2]; b[3] = (__bf16)v[3];
  *(bf16x4*)(dst + o) = b;
}

// =====================================================================
// gemm_kv: y=0: Kp[n][d] = E@Wk^T;  y=1: Vtile[g][d][n] = E@Wv^T
//          y=2 (x<8): Qw = T@Wq^T  (small path, reuses LDS)
// 128 E-rows x 256 W-rows per block, K=512, BK=32.
// E staged via regs (f32->bf16) into PADDED Et tile (stride 40) -> no
// 16-way bank conflicts. W staged via cp16.
// =====================================================================
#define ETS 40   // Et row stride in elems (80 B -> bank spread)
__global__ __launch_bounds__(256) void gemm_kv(const float* __restrict__ E,
                                               const __bf16* __restrict__ Wkv,
                                               const __bf16* __restrict__ Wqb,
                                               const __bf16* __restrict__ Tbf,
                                               __bf16* __restrict__ Kp,
                                               __bf16* __restrict__ Vtile,
                                               __bf16* __restrict__ Qw) {
  __shared__ __align__(16) char smem[26624];
  __bf16* Wt = (__bf16*)smem;              // 256x32 bf16 = 16384 B
  __bf16* Et = (__bf16*)(smem + 16384);    // 128x40 bf16 = 10240 B

  const int tid = threadIdx.x;
  const int lane = tid & 63;
  const int q = lane >> 4, ln = lane & 15;
  const int w = tid >> 6;
  const int yy = blockIdx.y;

  if (yy == 2) {
    // ---- small Q GEMM: out[n*256+m], A=Wqb(256x512), B=Tbf(512x512) ----
    if (blockIdx.x >= 8) return;
    __bf16* At = Wt;            // 128x32 = 8192 B
    __bf16* Bt = Wt + 4096;     // 128x32 = 8192 B
    const int nbase = (blockIdx.x & 3) * 128;
    const int mbase = (blockIdx.x >> 2) * 128;
    const int wm = w >> 1, wn = w & 1;
    f32x4 acc[4][4] = {};
    for (int kt = 0; kt < 16; ++kt) {
      const int k0 = kt * 32;
      __syncthreads();
#pragma unroll
      for (int s = 0; s < 2; ++s) {
        const int cbase = (tid & 192) + s * 256;
        const int c = cbase + lane;
        const int row = c >> 2;
        const int kc = (c & 3) * 8;
        cp16(&At[cbase * 8], Wqb + (size_t)(mbase + row) * 512 + k0 + kc);
        cp16(&Bt[cbase * 8], Tbf + (size_t)(nbase + row) * 512 + k0 + kc);
      }
      __syncthreads();
      bf16x8 af[4], bfr[4];
#pragma unroll
      for (int f = 0; f < 4; ++f) {
        af[f]  = *(const bf16x8*)&At[(wm * 64 + f * 16 + ln) * 32 + q * 8];
        bfr[f] = *(const bf16x8*)&Bt[(wn * 64 + f * 16 + ln) * 32 + q * 8];
      }
#pragma unroll
      for (int fm = 0; fm < 4; ++fm)
#pragma unroll
        for (int fn = 0; fn < 4; ++fn)
          acc[fm][fn] = __builtin_amdgcn_mfma_f32_16x16x32_bf16(
              af[fm], bfr[fn], acc[fm][fn], 0, 0, 0);
    }
#pragma unroll
    for (int fm = 0; fm < 4; ++fm)
#pragma unroll
      for (int fn = 0; fn < 4; ++fn) {
        const int m = mbase + wm * 64 + fm * 16 + q * 4;
        const int n = nbase + wn * 64 + fn * 16 + ln;
        f32x4 v = acc[fm][fn];
        bf16x4 o;
        o[0] = (__bf16)v[0]; o[1] = (__bf16)v[1];
        o[2] = (__bf16)v[2]; o[3] = (__bf16)v[3];
        *(bf16x4*)&Qw[(size_t)n * 256 + m] = o;
      }
    return;
  }

  // ---- main KV path ----
  const int wm = w >> 1, wn = w & 1;
  const int nbase = blockIdx.x * 128;
  const __bf16* Wb = Wkv + yy * 131072;   // 256 rows x 512

  f32x4 acc[8][4] = {};

  for (int kt = 0; kt < 16; ++kt) {
    const int k0 = kt * 32;
    __syncthreads();
    // W: 1024 cp16 chunks
#pragma unroll
    for (int s = 0; s < 4; ++s) {
      const int cbase = (tid & 192) + s * 256;
      const int c = cbase + lane;
      const int wrow = c >> 2, wkc = (c & 3) * 8;
      cp16(&Wt[cbase * 8], Wb + (size_t)wrow * 512 + k0 + wkc);
    }
    // E: reg-staged with cvt, padded rows
    f32x4 ev[4];
#pragma unroll
    for (int s = 0; s < 4; ++s) {
      const int c = tid + s * 256;
      const int row = c >> 3, col = (c & 7) * 4;
      ev[s] = *(const f32x4*)(E + (size_t)(nbase + row) * 512 + k0 + col);
    }
#pragma unroll
    for (int s = 0; s < 4; ++s) {
      const int c = tid + s * 256;
      const int row = c >> 3, col = (c & 7) * 4;
      bf16x4 b;
      b[0] = (__bf16)ev[s][0]; b[1] = (__bf16)ev[s][1];
      b[2] = (__bf16)ev[s][2]; b[3] = (__bf16)ev[s][3];
      *(bf16x4*)&Et[row * ETS + col] = b;
    }
    __syncthreads();

    bf16x8 af[8];
#pragma unroll
    for (int fm = 0; fm < 8; ++fm)
      af[fm] = *(const bf16x8*)&Wt[(wm * 128 + fm * 16 + ln) * 32 + q * 8];
    bf16x8 bfr[4];
#pragma unroll
    for (int fn = 0; fn < 4; ++fn)
      bfr[fn] = *(const bf16x8*)&Et[(wn * 64 + fn * 16 + ln) * ETS + q * 8];
#pragma unroll
    for (int fm = 0; fm < 8; ++fm)
#pragma unroll
      for (int fn = 0; fn < 4; ++fn)
        acc[fm][fn] = __builtin_amdgcn_mfma_f32_16x16x32_bf16(
            af[fm], bfr[fn], acc[fm][fn], 0, 0, 0);
  }

  if (yy == 0) {
    // Kp[n*256 + m]: lane holds m = base+q*4+r consecutive -> 8B stores
#pragma unroll
    for (int fm = 0; fm < 8; ++fm)
#pragma unroll
      for (int fn = 0; fn < 4; ++fn) {
        const int m = wm * 128 + fm * 16 + q * 4;
        const int n = nbase + wn * 64 + fn * 16 + ln;
        f32x4 v = acc[fm][fn];
        bf16x4 o;
        o[0] = (__bf16)v[0]; o[1] = (__bf16)v[1];
        o[2] = (__bf16)v[2]; o[3] = (__bf16)v[3];
        *(bf16x4*)&Kp[(size_t)n * 256 + m] = o;
      }
  } else {
    // Vtile[g][d][n_local]: g = blockIdx.x
    __bf16* Vp = Vtile + (size_t)blockIdx.x * 32768;
#pragma unroll
    for (int fm = 0; fm < 8; ++fm)
#pragma unroll
      for (int fn = 0; fn < 4; ++fn) {
        const int nl = wn * 64 + fn * 16 + ln;
        f32x4 v = acc[fm][fn];
#pragma unroll
        for (int r = 0; r < 4; ++r) {
          const int d = wm * 128 + fm * 16 + q * 4 + r;
          Vp[d * 128 + nl] = (__bf16)v[r];
        }
      }
  }
}

// =====================================================================
// Attention: per (cx 128-n chunk, batch b): S = Q Kp^T/16 + logP,
// P = exp(S) (scores tiny, logP in [-2.3,-0.105] -> no max pass).
// Writes Pws (bf16 unnormalized), rowsum (atomic), Opart plane cx.
// PV B-operand staged from Vtile via cp16 (no global scatter).
// =====================================================================
#define QLDS_STRIDE 264
#define PLDS_STRIDE 136
__global__ __launch_bounds__(256) void attn_kernel(
    const __bf16* __restrict__ Qw, const __bf16* __restrict__ Kp,
    const __bf16* __restrict__ Vtile, const float* __restrict__ Pb,
    __bf16* __restrict__ Pws, float* __restrict__ Opart,
    float* __restrict__ rowsum) {
  __shared__ __align__(16) __bf16 Qlds[32 * QLDS_STRIDE];   // 16896 B
  __shared__ __align__(16) __bf16 Ktile[128 * 32];          //  8192 B
  __shared__ __align__(16) __bf16 Plds[32 * PLDS_STRIDE];   //  8704 B
  __shared__ __align__(16) __bf16 Vl[256 * 32];             // 16384 B

  const int tid = threadIdx.x;
  const int lane = tid & 63;
  const int w = tid >> 6;
  const int q = lane >> 4, ln = lane & 15;
  const int b = blockIdx.y;
  const int cx = blockIdx.x;
  const int n0 = cx * 128;

  // stage Q_b [32 x 256] into padded LDS
  const __bf16* Qb = Qw + (size_t)b * 32 * 256;
#pragma unroll
  for (int s = 0; s < 4; ++s) {
    const int c = tid + s * 256;
    const int row = c >> 5, col = (c & 31) * 8;
    bf16x8 v = *(const bf16x8*)(Qb + (size_t)c * 8);
    *(bf16x8*)&Qlds[row * QLDS_STRIDE + col] = v;
  }

  // ---- QK^T ----
  f32x4 acc[2][2] = {};
  const __bf16* Kpb = Kp + (size_t)(b * 4096 + n0) * 256;
  for (int kk = 0; kk < 8; ++kk) {
    __syncthreads();
#pragma unroll
    for (int s = 0; s < 2; ++s) {
      const int cbase = (tid & 192) + s * 256;
      const int c = cbase + lane;
      const int row = c >> 2;
      const int kc = (c & 3) * 8;
      cp16(&Ktile[cbase * 8], Kpb + (size_t)row * 256 + kk * 32 + kc);
    }
    __syncthreads();
    bf16x8 a0 = *(const bf16x8*)&Qlds[(ln) * QLDS_STRIDE + kk * 32 + q * 8];
    bf16x8 a1 = *(const bf16x8*)&Qlds[(16 + ln) * QLDS_STRIDE + kk * 32 + q * 8];
    bf16x8 b0 = *(const bf16x8*)&Ktile[(w * 32 + ln) * 32 + q * 8];
    bf16x8 b1 = *(const bf16x8*)&Ktile[(w * 32 + 16 + ln) * 32 + q * 8];
    acc[0][0] = __builtin_amdgcn_mfma_f32_16x16x32_bf16(a0, b0, acc[0][0], 0, 0, 0);
    acc[0][1] = __builtin_amdgcn_mfma_f32_16x16x32_bf16(a0, b1, acc[0][1], 0, 0, 0);
    acc[1][0] = __builtin_amdgcn_mfma_f32_16x16x32_bf16(a1, b0, acc[1][0], 0, 0, 0);
    acc[1][1] = __builtin_amdgcn_mfma_f32_16x16x32_bf16(a1, b1, acc[1][1], 0, 0, 0);
  }

  // ---- P = exp(S/16 + logP) ----
  float lp[2];
#pragma unroll
  for (int fn = 0; fn < 2; ++fn) {
    const int n = n0 + w * 32 + fn * 16 + ln;
    float p = Pb[b * 4096 + n];
    p = fminf(fmaxf(p, 0.1f), 0.9f);
    lp[fn] = __logf(p);
  }
  float rs[2][4] = {};
#pragma unroll
  for (int fm = 0; fm < 2; ++fm) {
#pragma unroll
    for (int fn = 0; fn < 2; ++fn) {
      f32x4 s = acc[fm][fn];
#pragma unroll
      for (int r = 0; r < 4; ++r) {
        const float pv = __expf(s[r] * 0.0625f + lp[fn]);
        const int i = fm * 16 + q * 4 + r;
        const int nn = w * 32 + fn * 16 + ln;
        const __bf16 pbv = (__bf16)pv;
        Pws[(size_t)(b * 32 + i) * 4096 + n0 + nn] = pbv;
        Plds[i * PLDS_STRIDE + nn] = pbv;
        rs[fm][r] += pv;
      }
    }
  }
#pragma unroll
  for (int m = 1; m < 16; m <<= 1)
#pragma unroll
    for (int fm = 0; fm < 2; ++fm)
#pragma unroll
      for (int r = 0; r < 4; ++r)
        rs[fm][r] += __shfl_xor(rs[fm][r], m, 64);
  if (ln == 0) {
#pragma unroll
    for (int fm = 0; fm < 2; ++fm)
#pragma unroll
      for (int r = 0; r < 4; ++r)
        atomicAdd(&rowsum[b * 32 + fm * 16 + q * 4 + r], rs[fm][r]);
  }

  // ---- PV: D2[i][d] = sum_n P[i][n] * V[n][d], V from Vtile plane ----
  f32x4 acc2[2][4] = {};
  const __bf16* Vplane = Vtile + (size_t)(b * 32 + cx) * 32768;
  for (int kk = 0; kk < 4; ++kk) {
    __syncthreads();
#pragma unroll
    for (int s = 0; s < 4; ++s) {
      const int cbase = (tid & 192) + s * 256;
      const int c = cbase + lane;
      const int d = c >> 2, nc = (c & 3) * 8;
      cp16(&Vl[cbase * 8], Vplane + (size_t)d * 128 + kk * 32 + nc);
    }
    __syncthreads();
    bf16x8 pa0 = *(const bf16x8*)&Plds[(ln) * PLDS_STRIDE + kk * 32 + q * 8];
    bf16x8 pa1 = *(const bf16x8*)&Plds[(16 + ln) * PLDS_STRIDE + kk * 32 + q * 8];
#pragma unroll
    for (int fd = 0; fd < 4; ++fd) {
      bf16x8 vb = *(const bf16x8*)&Vl[(w * 64 + fd * 16 + ln) * 32 + q * 8];
      acc2[0][fd] = __builtin_amdgcn_mfma_f32_16x16x32_bf16(pa0, vb, acc2[0][fd], 0, 0, 0);
      acc2[1][fd] = __builtin_amdgcn_mfma_f32_16x16x32_bf16(pa1, vb, acc2[1][fd], 0, 0, 0);
    }
  }
  float* Op = Opart + (size_t)cx * 131072;
#pragma unroll
  for (int fm = 0; fm < 2; ++fm)
#pragma unroll
    for (int fd = 0; fd < 4; ++fd)
#pragma unroll
      for (int r = 0; r < 4; ++r) {
        const int i = fm * 16 + q * 4 + r;
        const int d = w * 64 + fd * 16 + ln;
        Op[(size_t)(b * 32 + i) * 256 + d] = acc2[fm][fd][r];
      }
}

// =====================================================================
// norm_p: A(f32) = Pws(bf16) / rowsum[row].
// =====================================================================
__global__ __launch_bounds__(256) void norm_p(const __bf16* __restrict__ Pws,
                                              const float* __restrict__ rowsum,
                                              float* __restrict__ Aout) {
  const size_t idx = ((size_t)blockIdx.x * 256 + threadIdx.x) * 4;
  const int row = (int)(idx >> 12);
  const float invs = 1.0f / rowsum[row];
  bf16x4 p = *(const bf16x4*)(Pws + idx);
  f32x4 o;
  o[0] = (float)p[0] * invs; o[1] = (float)p[1] * invs;
  o[2] = (float)p[2] * invs; o[3] = (float)p[3] * invs;
  *(f32x4*)(Aout + idx) = o;
}

// =====================================================================
// final: reduce 32 Opart planes -> F1; F2 = (F1/rowsum)@Wo^T; L2 norm.
// =====================================================================
__global__ __launch_bounds__(256) void final_kernel(const float* __restrict__ Opart,
                                                    const float* __restrict__ rowsum,
                                                    const float* __restrict__ Wo,
                                                    float* __restrict__ Fout) {
  __shared__ float fl[256];
  __shared__ float redbuf[4];
  const int row = blockIdx.x;
  const int t = threadIdx.x;
  float s = 0.f;
#pragma unroll
  for (int c = 0; c < 32; ++c)
    s += Opart[(size_t)c * 131072 + (size_t)row * 256 + t];
  fl[t] = s;
  __syncthreads();
  const float invs = 1.0f / rowsum[row];
  float f2[2];
#pragma unroll
  for (int h = 0; h < 2; ++h) {
    const int m = t + h * 256;
    const float* wr = Wo + (size_t)m * 256;
    float dot = 0.f;
    for (int d = 0; d < 256; d += 4) {
      f32x4 wv = *(const f32x4*)(wr + d);
      dot += wv[0] * fl[d] + wv[1] * fl[d + 1] + wv[2] * fl[d + 2] + wv[3] * fl[d + 3];
    }
    f2[h] = dot * invs;
  }
  float ps = f2[0] * f2[0] + f2[1] * f2[1];
#pragma unroll
  for (int m = 1; m < 64; m <<= 1) ps += __shfl_xor(ps, m, 64);
  if ((t & 63) == 0) redbuf[t >> 6] = ps;
  __syncthreads();
  const float tot = redbuf[0] + redbuf[1] + redbuf[2] + redbuf[3];
  const float sc = 1.0f / (sqrtf(tot) + 1e-8f);
  Fout[(size_t)row * 512 + t] = f2[0] * sc;
  Fout[(size_t)row * 512 + t + 256] = f2[1] * sc;
}

// =====================================================================
extern "C" void kernel_launch(void* const* d_in, const int* in_sizes, int n_in,
                              void* d_out, int out_size, void* d_ws, size_t ws_size,
                              hipStream_t stream) {
  const float* E  = (const float*)d_in[0];  // [16,4096,512]
  const float* T  = (const float*)d_in[1];  // [16,32,512]
  const float* Pb = (const float*)d_in[2];  // [16,4096]
  const float* Wq = (const float*)d_in[3];  // [256,512]
  const float* Wk = (const float*)d_in[4];
  const float* Wv = (const float*)d_in[5];
  const float* Wo = (const float*)d_in[6];  // [512,256]

  float* out  = (float*)d_out;
  float* Fout = out;             // [512][512] f32
  float* Aout = out + 262144;    // [512][4096] f32

  char* ws = (char*)d_ws;
  __bf16* Kp    = (__bf16*)ws;                  // [65536][256] bf16  33554432 B
  __bf16* Vtile = (__bf16*)(ws + 33554432);     // [512][256][128]    33554432 B
  __bf16* Pws   = (__bf16*)(ws + 67108864);     // [512][4096] bf16    4194304 B
  float*  Opart = (float*)(ws + 71303168);      // [32][512][256] f32 16777216 B
  __bf16* Tbf   = (__bf16*)(ws + 88080384);     //                      524288 B
  __bf16* Wqb   = (__bf16*)(ws + 88604672);     //                      262144 B
  __bf16* Wkvb  = (__bf16*)(ws + 88866816);     //                      524288 B
  __bf16* Qw    = (__bf16*)(ws + 89391104);     // [512][256] bf16      262144 B
  float*  rowsum = (float*)(ws + 89653248);     // [512] f32 (2048 B)

  hipMemsetAsync(rowsum, 0, 2048, stream);

  cvt_small<<<640, 256, 0, stream>>>(Wq, Wk, Wv, T, Wqb, Wkvb, Tbf);

  // Kp (y=0), Vtile (y=1), Qw (y=2, x<8) in one launch
  gemm_kv<<<dim3(512, 3), 256, 0, stream>>>(E, Wkvb, Wqb, Tbf, Kp, Vtile, Qw);

  attn_kernel<<<dim3(32, 16), 256, 0, stream>>>(Qw, Kp, Vtile, Pb, Pws, Opart, rowsum);
  norm_p<<<2048, 256, 0, stream>>>(Pws, rowsum, Aout);
  final_kernel<<<512, 256, 0, stream>>>(Opart, rowsum, Wo, Fout);
}

// Round 7
// 349.467 us; speedup vs baseline: 1.1319x; 1.0856x over previous
//
#include <hip/hip_runtime.h>

// ---------- types ----------
typedef __bf16 bf16x8 __attribute__((ext_vector_type(8)));
typedef __bf16 bf16x4 __attribute__((ext_vector_type(4)));
typedef float  f32x4  __attribute__((ext_vector_type(4)));

// async global->LDS, 16B per lane; LDS dest = wave-uniform base + lane*16
__device__ __forceinline__ void cp16(void* lds, const void* g) {
  __builtin_amdgcn_global_load_lds(
      (const __attribute__((address_space(1))) unsigned int*)g,
      (__attribute__((address_space(3))) unsigned int*)lds, 16, 0, 0);
}

// =====================================================================
// Fused small conversions: Wq->Wqb, Wk->Wkvb[0:], Wv->Wkvb[131072:], T->Tbf
// =====================================================================
__global__ __launch_bounds__(256) void cvt_small(const float* __restrict__ Wq,
                                                 const float* __restrict__ Wk,
                                                 const float* __restrict__ Wv,
                                                 const float* __restrict__ T,
                                                 __bf16* __restrict__ Wqb,
                                                 __bf16* __restrict__ Wkvb,
                                                 __bf16* __restrict__ Tbf) {
  const int idx = (blockIdx.x * 256 + threadIdx.x) * 4;
  const float* src;
  __bf16* dst;
  int o;
  if (idx < 131072)      { o = idx;          src = Wq; dst = Wqb; }
  else if (idx < 262144) { o = idx - 131072; src = Wk; dst = Wkvb; }
  else if (idx < 393216) { o = idx - 262144; src = Wv; dst = Wkvb + 131072; }
  else                   { o = idx - 393216; src = T;  dst = Tbf; }
  f32x4 v = *(const f32x4*)(src + o);
  bf16x4 b;
  b[0] = (__bf16)v[0]; b[1] = (__bf16)v[1];
  b[2] = (__bf16)v[2]; b[3] = (__bf16)v[3];
  *(bf16x4*)(dst + o) = b;
}

// =====================================================================
// gemm_kv: 256m x 64n tile, K=512, BK=32. acc[8][2] = 64 AGPR.
//   y=0, x<1024 : Kp[n][d]    = E@Wk^T
//   y=1, x<1024 : Vtile[g][d][n] = E@Wv^T
//   y=0, x in [1024,1032): Qw = T@Wq^T (m97 128x128 path)
// launch_bounds(256,2): cap regs so 2 waves/SIMD (2 blocks/CU) survive.
// =====================================================================
#define ETS 40   // Et row stride (elems): 80 B -> bank spread
__global__ __launch_bounds__(256, 2) void gemm_kv(const float* __restrict__ E,
                                                  const __bf16* __restrict__ Wkv,
                                                  const __bf16* __restrict__ Wqb,
                                                  const __bf16* __restrict__ Tbf,
                                                  __bf16* __restrict__ Kp,
                                                  __bf16* __restrict__ Vtile,
                                                  __bf16* __restrict__ Qw) {
  __shared__ __align__(16) char smem[21504];
  __bf16* Wt = (__bf16*)smem;              // 256x32 bf16 = 16384 B
  __bf16* Et = (__bf16*)(smem + 16384);    // 64x40  bf16 =  5120 B

  const int tid = threadIdx.x;
  const int lane = tid & 63;
  const int q = lane >> 4, ln = lane & 15;
  const int w = tid >> 6;
  const int yy = blockIdx.y;
  const int bx = blockIdx.x;

  if (bx >= 1024) {
    // ---- small Q GEMM ----
    if (yy == 1) return;
    const int t = bx - 1024;               // 0..7
    __bf16* At = Wt;                       // 128x32
    __bf16* Bt = Wt + 4096;                // 128x32
    const int nbase = (t & 3) * 128;
    const int mbase = (t >> 2) * 128;
    const int wm = w >> 1, wn = w & 1;
    f32x4 acc[4][4] = {};
    for (int kt = 0; kt < 16; ++kt) {
      const int k0 = kt * 32;
      __syncthreads();
#pragma unroll
      for (int s = 0; s < 2; ++s) {
        const int cbase = (tid & 192) + s * 256;
        const int c = cbase + lane;
        const int row = c >> 2;
        const int kc = (c & 3) * 8;
        cp16(&At[cbase * 8], Wqb + (size_t)(mbase + row) * 512 + k0 + kc);
        cp16(&Bt[cbase * 8], Tbf + (size_t)(nbase + row) * 512 + k0 + kc);
      }
      __syncthreads();
      bf16x8 af[4], bfr[4];
#pragma unroll
      for (int f = 0; f < 4; ++f) {
        af[f]  = *(const bf16x8*)&At[(wm * 64 + f * 16 + ln) * 32 + q * 8];
        bfr[f] = *(const bf16x8*)&Bt[(wn * 64 + f * 16 + ln) * 32 + q * 8];
      }
#pragma unroll
      for (int fm = 0; fm < 4; ++fm)
#pragma unroll
        for (int fn = 0; fn < 4; ++fn)
          acc[fm][fn] = __builtin_amdgcn_mfma_f32_16x16x32_bf16(
              af[fm], bfr[fn], acc[fm][fn], 0, 0, 0);
    }
#pragma unroll
    for (int fm = 0; fm < 4; ++fm)
#pragma unroll
      for (int fn = 0; fn < 4; ++fn) {
        const int m = mbase + wm * 64 + fm * 16 + q * 4;
        const int n = nbase + wn * 64 + fn * 16 + ln;
        f32x4 v = acc[fm][fn];
        bf16x4 o;
        o[0] = (__bf16)v[0]; o[1] = (__bf16)v[1];
        o[2] = (__bf16)v[2]; o[3] = (__bf16)v[3];
        *(bf16x4*)&Qw[(size_t)n * 256 + m] = o;
      }
    return;
  }

  // ---- main KV path: 256m x 64n ----
  const int wm = w >> 1, wn = w & 1;
  const int nbase = bx * 64;
  const __bf16* Wb = Wkv + yy * 131072;    // 256 rows x 512

  f32x4 acc[8][2] = {};

  for (int kt = 0; kt < 16; ++kt) {
    const int k0 = kt * 32;
    __syncthreads();
    // Wt: 1024 cp16 chunks (16 KB)
#pragma unroll
    for (int s = 0; s < 4; ++s) {
      const int cbase = (tid & 192) + s * 256;
      const int c = cbase + lane;
      const int wrow = c >> 2, wkc = (c & 3) * 8;
      cp16(&Wt[cbase * 8], Wb + (size_t)wrow * 512 + k0 + wkc);
    }
    // Et: 64x32 f32, reg-staged -> bf16 padded LDS
    f32x4 ev[2];
#pragma unroll
    for (int s = 0; s < 2; ++s) {
      const int c = tid + s * 256;          // 512 chunks of 4 f32
      const int row = c >> 3, col = (c & 7) * 4;
      ev[s] = *(const f32x4*)(E + (size_t)(nbase + row) * 512 + k0 + col);
    }
#pragma unroll
    for (int s = 0; s < 2; ++s) {
      const int c = tid + s * 256;
      const int row = c >> 3, col = (c & 7) * 4;
      bf16x4 b;
      b[0] = (__bf16)ev[s][0]; b[1] = (__bf16)ev[s][1];
      b[2] = (__bf16)ev[s][2]; b[3] = (__bf16)ev[s][3];
      *(bf16x4*)&Et[row * ETS + col] = b;
    }
    __syncthreads();

    bf16x8 bfr[2];
#pragma unroll
    for (int fn = 0; fn < 2; ++fn)
      bfr[fn] = *(const bf16x8*)&Et[(wn * 32 + fn * 16 + ln) * ETS + q * 8];
#pragma unroll
    for (int fm = 0; fm < 8; ++fm) {
      bf16x8 af = *(const bf16x8*)&Wt[(wm * 128 + fm * 16 + ln) * 32 + q * 8];
#pragma unroll
      for (int fn = 0; fn < 2; ++fn)
        acc[fm][fn] = __builtin_amdgcn_mfma_f32_16x16x32_bf16(
            af, bfr[fn], acc[fm][fn], 0, 0, 0);
    }
  }

  if (yy == 0) {
    // Kp[n*256 + m]: m = base+q*4+r consecutive -> 8B stores
#pragma unroll
    for (int fm = 0; fm < 8; ++fm)
#pragma unroll
      for (int fn = 0; fn < 2; ++fn) {
        const int m = wm * 128 + fm * 16 + q * 4;
        const int n = nbase + wn * 32 + fn * 16 + ln;
        f32x4 v = acc[fm][fn];
        bf16x4 o;
        o[0] = (__bf16)v[0]; o[1] = (__bf16)v[1];
        o[2] = (__bf16)v[2]; o[3] = (__bf16)v[3];
        *(bf16x4*)&Kp[(size_t)n * 256 + m] = o;
      }
  } else {
    // Vtile[g][d][nl]: g = bx>>1, nl = (bx&1)*64 + local n
    __bf16* Vp = Vtile + (size_t)(bx >> 1) * 32768;
    const int noff = (bx & 1) * 64;
#pragma unroll
    for (int fm = 0; fm < 8; ++fm)
#pragma unroll
      for (int fn = 0; fn < 2; ++fn) {
        const int nl = noff + wn * 32 + fn * 16 + ln;
        f32x4 v = acc[fm][fn];
#pragma unroll
        for (int r = 0; r < 4; ++r) {
          const int d = wm * 128 + fm * 16 + q * 4 + r;
          Vp[d * 128 + nl] = (__bf16)v[r];
        }
      }
  }
}

// =====================================================================
// Attention, whole-tile staged: per (cx, b):
//   stage Q (17KB, reg), K-tile (64KB = 4096 cp16 chunks -> [kk][n][32]),
//   V-plane (64KB = 4096 cp16 chunks -> [kk][d][32]); ONE barrier;
//   QK^T (8 kk); P=exp(S/16+logP) (no max pass: scores tiny, logP in
//   [-2.3,-0.105]); barrier; PV (4 kk); store Opart. 2 barriers total.
// =====================================================================
#define QLDS_STRIDE 264
#define PLDS_STRIDE 136
__global__ __launch_bounds__(256) void attn_kernel(
    const __bf16* __restrict__ Qw, const __bf16* __restrict__ Kp,
    const __bf16* __restrict__ Vtile, const float* __restrict__ Pb,
    __bf16* __restrict__ Pws, float* __restrict__ Opart,
    float* __restrict__ rowsum) {
  __shared__ __align__(16) __bf16 Qlds[32 * QLDS_STRIDE];   // 16896 B
  __shared__ __align__(16) __bf16 Kl[8 * 128 * 32];         // 65536 B
  __shared__ __align__(16) __bf16 Vl[4 * 256 * 32];         // 65536 B
  __shared__ __align__(16) __bf16 Plds[32 * PLDS_STRIDE];   //  8704 B

  const int tid = threadIdx.x;
  const int lane = tid & 63;
  const int w = tid >> 6;
  const int q = lane >> 4, ln = lane & 15;
  const int b = blockIdx.y;
  const int cx = blockIdx.x;
  const int n0 = cx * 128;

  // ---- stage K-tile: 4096 chunks, layout [kk][row][jc] ----
  const __bf16* Kpb = Kp + (size_t)(b * 4096 + n0) * 256;
#pragma unroll
  for (int s = 0; s < 16; ++s) {
    const int cbase = (tid & 192) + s * 256;
    const int c = cbase + lane;
    const int kk = c >> 9, row = (c >> 2) & 127, jc = c & 3;
    cp16(&Kl[cbase * 8], Kpb + (size_t)row * 256 + kk * 32 + jc * 8);
  }
  // ---- stage V-plane: 4096 chunks (65536 B!), layout [kk][d][jc] ----
  const __bf16* Vplane = Vtile + (size_t)(b * 32 + cx) * 32768;
#pragma unroll
  for (int s = 0; s < 16; ++s) {
    const int cbase = (tid & 192) + s * 256;
    const int c = cbase + lane;
    const int kk = c >> 10, d = (c >> 2) & 255, jc = c & 3;
    cp16(&Vl[cbase * 8], Vplane + (size_t)d * 128 + kk * 32 + jc * 8);
  }
  // ---- stage Q_b [32 x 256] (reg -> padded LDS) ----
  const __bf16* Qb = Qw + (size_t)b * 32 * 256;
#pragma unroll
  for (int s = 0; s < 4; ++s) {
    const int c = tid + s * 256;
    const int row = c >> 5, col = (c & 31) * 8;
    bf16x8 v = *(const bf16x8*)(Qb + (size_t)c * 8);
    *(bf16x8*)&Qlds[row * QLDS_STRIDE + col] = v;
  }
  __syncthreads();

  // ---- QK^T: D[i][n], 2 i-frags x 2 n-frags per wave ----
  f32x4 acc[2][2] = {};
  for (int kk = 0; kk < 8; ++kk) {
    bf16x8 a0 = *(const bf16x8*)&Qlds[(ln) * QLDS_STRIDE + kk * 32 + q * 8];
    bf16x8 a1 = *(const bf16x8*)&Qlds[(16 + ln) * QLDS_STRIDE + kk * 32 + q * 8];
    bf16x8 b0 = *(const bf16x8*)&Kl[kk * 4096 + (w * 32 + ln) * 32 + q * 8];
    bf16x8 b1 = *(const bf16x8*)&Kl[kk * 4096 + (w * 32 + 16 + ln) * 32 + q * 8];
    acc[0][0] = __builtin_amdgcn_mfma_f32_16x16x32_bf16(a0, b0, acc[0][0], 0, 0, 0);
    acc[0][1] = __builtin_amdgcn_mfma_f32_16x16x32_bf16(a0, b1, acc[0][1], 0, 0, 0);
    acc[1][0] = __builtin_amdgcn_mfma_f32_16x16x32_bf16(a1, b0, acc[1][0], 0, 0, 0);
    acc[1][1] = __builtin_amdgcn_mfma_f32_16x16x32_bf16(a1, b1, acc[1][1], 0, 0, 0);
  }

  // ---- P = exp(S/16 + logP) ----
  float lp[2];
#pragma unroll
  for (int fn = 0; fn < 2; ++fn) {
    const int n = n0 + w * 32 + fn * 16 + ln;
    float p = Pb[b * 4096 + n];
    p = fminf(fmaxf(p, 0.1f), 0.9f);
    lp[fn] = __logf(p);
  }
  float rs[2][4] = {};
#pragma unroll
  for (int fm = 0; fm < 2; ++fm) {
#pragma unroll
    for (int fn = 0; fn < 2; ++fn) {
      f32x4 s = acc[fm][fn];
#pragma unroll
      for (int r = 0; r < 4; ++r) {
        const float pv = __expf(s[r] * 0.0625f + lp[fn]);
        const int i = fm * 16 + q * 4 + r;
        const int nn = w * 32 + fn * 16 + ln;
        const __bf16 pbv = (__bf16)pv;
        Pws[(size_t)(b * 32 + i) * 4096 + n0 + nn] = pbv;
        Plds[i * PLDS_STRIDE + nn] = pbv;
        rs[fm][r] += pv;
      }
    }
  }
#pragma unroll
  for (int m = 1; m < 16; m <<= 1)
#pragma unroll
    for (int fm = 0; fm < 2; ++fm)
#pragma unroll
      for (int r = 0; r < 4; ++r)
        rs[fm][r] += __shfl_xor(rs[fm][r], m, 64);
  if (ln == 0) {
#pragma unroll
    for (int fm = 0; fm < 2; ++fm)
#pragma unroll
      for (int r = 0; r < 4; ++r)
        atomicAdd(&rowsum[b * 32 + fm * 16 + q * 4 + r], rs[fm][r]);
  }
  __syncthreads();

  // ---- PV: D2[i][d] = sum_n P[i][n] * V[n][d] ----
  f32x4 acc2[2][4] = {};
  for (int kk = 0; kk < 4; ++kk) {
    bf16x8 pa0 = *(const bf16x8*)&Plds[(ln) * PLDS_STRIDE + kk * 32 + q * 8];
    bf16x8 pa1 = *(const bf16x8*)&Plds[(16 + ln) * PLDS_STRIDE + kk * 32 + q * 8];
#pragma unroll
    for (int fd = 0; fd < 4; ++fd) {
      bf16x8 vb = *(const bf16x8*)&Vl[kk * 8192 + (w * 64 + fd * 16 + ln) * 32 + q * 8];
      acc2[0][fd] = __builtin_amdgcn_mfma_f32_16x16x32_bf16(pa0, vb, acc2[0][fd], 0, 0, 0);
      acc2[1][fd] = __builtin_amdgcn_mfma_f32_16x16x32_bf16(pa1, vb, acc2[1][fd], 0, 0, 0);
    }
  }
  float* Op = Opart + (size_t)cx * 131072;
#pragma unroll
  for (int fm = 0; fm < 2; ++fm)
#pragma unroll
    for (int fd = 0; fd < 4; ++fd)
#pragma unroll
      for (int r = 0; r < 4; ++r) {
        const int i = fm * 16 + q * 4 + r;
        const int d = w * 64 + fd * 16 + ln;
        Op[(size_t)(b * 32 + i) * 256 + d] = acc2[fm][fd][r];
      }
}

// =====================================================================
// norm_p: A(f32) = Pws(bf16) / rowsum[row].
// =====================================================================
__global__ __launch_bounds__(256) void norm_p(const __bf16* __restrict__ Pws,
                                              const float* __restrict__ rowsum,
                                              float* __restrict__ Aout) {
  const size_t idx = ((size_t)blockIdx.x * 256 + threadIdx.x) * 4;
  const int row = (int)(idx >> 12);
  const float invs = 1.0f / rowsum[row];
  bf16x4 p = *(const bf16x4*)(Pws + idx);
  f32x4 o;
  o[0] = (float)p[0] * invs; o[1] = (float)p[1] * invs;
  o[2] = (float)p[2] * invs; o[3] = (float)p[3] * invs;
  *(f32x4*)(Aout + idx) = o;
}

// =====================================================================
// final: reduce 32 Opart planes -> F1; F2 = (F1/rowsum)@Wo^T; L2 norm.
// =====================================================================
__global__ __launch_bounds__(256) void final_kernel(const float* __restrict__ Opart,
                                                    const float* __restrict__ rowsum,
                                                    const float* __restrict__ Wo,
                                                    float* __restrict__ Fout) {
  __shared__ float fl[256];
  __shared__ float redbuf[4];
  const int row = blockIdx.x;
  const int t = threadIdx.x;
  float s = 0.f;
#pragma unroll
  for (int c = 0; c < 32; ++c)
    s += Opart[(size_t)c * 131072 + (size_t)row * 256 + t];
  fl[t] = s;
  __syncthreads();
  const float invs = 1.0f / rowsum[row];
  float f2[2];
#pragma unroll
  for (int h = 0; h < 2; ++h) {
    const int m = t + h * 256;
    const float* wr = Wo + (size_t)m * 256;
    float dot = 0.f;
    for (int d = 0; d < 256; d += 4) {
      f32x4 wv = *(const f32x4*)(wr + d);
      dot += wv[0] * fl[d] + wv[1] * fl[d + 1] + wv[2] * fl[d + 2] + wv[3] * fl[d + 3];
    }
    f2[h] = dot * invs;
  }
  float ps = f2[0] * f2[0] + f2[1] * f2[1];
#pragma unroll
  for (int m = 1; m < 64; m <<= 1) ps += __shfl_xor(ps, m, 64);
  if ((t & 63) == 0) redbuf[t >> 6] = ps;
  __syncthreads();
  const float tot = redbuf[0] + redbuf[1] + redbuf[2] + redbuf[3];
  const float sc = 1.0f / (sqrtf(tot) + 1e-8f);
  Fout[(size_t)row * 512 + t] = f2[0] * sc;
  Fout[(size_t)row * 512 + t + 256] = f2[1] * sc;
}

// =====================================================================
extern "C" void kernel_launch(void* const* d_in, const int* in_sizes, int n_in,
                              void* d_out, int out_size, void* d_ws, size_t ws_size,
                              hipStream_t stream) {
  const float* E  = (const float*)d_in[0];  // [16,4096,512]
  const float* T  = (const float*)d_in[1];  // [16,32,512]
  const float* Pb = (const float*)d_in[2];  // [16,4096]
  const float* Wq = (const float*)d_in[3];  // [256,512]
  const float* Wk = (const float*)d_in[4];
  const float* Wv = (const float*)d_in[5];
  const float* Wo = (const float*)d_in[6];  // [512,256]

  float* out  = (float*)d_out;
  float* Fout = out;             // [512][512] f32
  float* Aout = out + 262144;    // [512][4096] f32

  char* ws = (char*)d_ws;
  __bf16* Kp    = (__bf16*)ws;                  // [65536][256] bf16  33554432 B
  __bf16* Vtile = (__bf16*)(ws + 33554432);     // [512][256][128]    33554432 B
  __bf16* Pws   = (__bf16*)(ws + 67108864);     // [512][4096] bf16    4194304 B
  float*  Opart = (float*)(ws + 71303168);      // [32][512][256] f32 16777216 B
  __bf16* Tbf   = (__bf16*)(ws + 88080384);     //                      524288 B
  __bf16* Wqb   = (__bf16*)(ws + 88604672);     //                      262144 B
  __bf16* Wkvb  = (__bf16*)(ws + 88866816);     //                      524288 B
  __bf16* Qw    = (__bf16*)(ws + 89391104);     // [512][256] bf16      262144 B
  float*  rowsum = (float*)(ws + 89653248);     // [512] f32 (2048 B)

  hipMemsetAsync(rowsum, 0, 2048, stream);

  cvt_small<<<640, 256, 0, stream>>>(Wq, Wk, Wv, T, Wqb, Wkvb, Tbf);

  // Kp (y=0), Vtile (y=1), Qw (y=0, x>=1024) in one launch
  gemm_kv<<<dim3(1032, 2), 256, 0, stream>>>(E, Wkvb, Wqb, Tbf, Kp, Vtile, Qw);

  attn_kernel<<<dim3(32, 16), 256, 0, stream>>>(Qw, Kp, Vtile, Pb, Pws, Opart, rowsum);
  norm_p<<<2048, 256, 0, stream>>>(Pws, rowsum, Aout);
  final_kernel<<<512, 256, 0, stream>>>(Opart, rowsum, Wo, Fout);
}